// Round 7
// baseline (43.905 us; speedup 1.0000x reference)
//
#include <hip/hip_runtime.h>

#define BATCH 64
#define CLSN 80
#define BBOXN 2
#define HWN (56 * 56)
#define NCELLS (BATCH * HWN)   // 200704
#define NTHR 256
#define NBLK (NCELLS / NTHR)   // 784, exact

// ws layout:
//   0  : unsigned ticket (memset to 0 each call)
//   64 : float4 partials[NBLK]  {neg, cls, resp, off}

__global__ __launch_bounds__(NTHR)
void yolo_onepass_kernel(const float* __restrict__ pred_cls,
                         const float* __restrict__ pred_resp,
                         const float* __restrict__ pred_box,
                         const float* __restrict__ label_cls,
                         const float* __restrict__ label_resp,
                         const float* __restrict__ label_box,
                         unsigned* __restrict__ ticket,
                         float4* __restrict__ partials,
                         float* __restrict__ out) {
    __shared__ int s_cnt;
    __shared__ int s_list[128];          // cbase = b*CLSN*HWN + yx per selected cell
    __shared__ int s_last;

    const int tid = threadIdx.x;
    if (tid == 0) s_cnt = 0;

    const int i = blockIdx.x * NTHR + tid;          // grid covers NCELLS exactly
    const int b = i / HWN;
    const int yx = i - b * HWN;
    const int rbase = b * (BBOXN * HWN) + yx;

    // coalesced: consecutive threads -> consecutive yx
    const float l0 = label_resp[rbase];
    const float l1 = label_resp[rbase + HWN];
    const float p0 = pred_resp[rbase];
    const float p1 = pred_resp[rbase + HWN];

    float negAcc = 0.0f, clsAcc = 0.0f, respAcc = 0.0f, offAcc = 0.0f;
    if (l0 < 1.0f) { float d = p0 - l0; negAcc += d * d; }
    if (l1 < 1.0f) { float d = p1 - l1; negAcc += d * d; }

    const bool sel = (l0 + l1) >= 0.5f;

    // ---- issue the scattered box loads EARLY; consume after the cls phase ----
    float t[8], p[8];
    if (sel) {
        const int bbase = b * (BBOXN * 4) * HWN + yx;
        #pragma unroll
        for (int k = 0; k < 8; ++k) {
            t[k] = label_box[bbase + k * HWN];
            p[k] = pred_box[bbase + k * HWN];
        }
    }

    __syncthreads();                     // s_cnt = 0 visible to all
    if (sel) {
        int slot = atomicAdd(&s_cnt, 1); // LDS atomic, ~2.6 per block
        s_list[slot] = b * (CLSN * HWN) + yx;
    }
    __syncthreads();
    const int nsel = s_cnt;              // block-uniform

    // ---- classification loss: block-cooperative, 3 cells x 80 classes/round,
    //      2 rounds unrolled so up to 4 independent loads are in flight ----
    const int cslot = tid / CLSN;        // 0..3 (3 full slots, tid<240)
    const int ccls  = tid - cslot * CLSN;
    const bool lane_ok = (tid < 3 * CLSN);
    for (int r = 0; r < nsel; r += 6) {
        const int sA = r + cslot;
        const int sB = r + cslot + 3;
        const bool aA = lane_ok && (sA < nsel);
        const bool aB = lane_ok && (sB < nsel);
        float pA = 0.0f, lA = 0.0f, pB = 0.0f, lB = 0.0f;
        if (aA) {
            const int ofs = s_list[sA] + ccls * HWN;
            pA = pred_cls[ofs]; lA = label_cls[ofs];
        }
        if (aB) {
            const int ofs = s_list[sB] + ccls * HWN;
            pB = pred_cls[ofs]; lB = label_cls[ofs];
        }
        if (aA) { float d = pA - lA; clsAcc += d * d; }
        if (aB) { float d = pB - lB; clsAcc += d * d; }
    }

    // ---- box / response loss: consume the early-issued loads ----
    if (sel) {
        float iou[2];
        #pragma unroll
        for (int bx = 0; bx < 2; ++bx) {
            float tx1 = t[bx * 4 + 0] - t[bx * 4 + 2] * 0.5f;
            float ty1 = t[bx * 4 + 1] - t[bx * 4 + 3] * 0.5f;
            float tx2 = tx1 + t[bx * 4 + 2];
            float ty2 = ty1 + t[bx * 4 + 3];
            float px1 = p[bx * 4 + 0] - p[bx * 4 + 2] * 0.5f;
            float py1 = p[bx * 4 + 1] - p[bx * 4 + 3] * 0.5f;
            float px2 = px1 + p[bx * 4 + 2];
            float py2 = py1 + p[bx * 4 + 3];
            float ltx = fmaxf(tx1, px1), lty = fmaxf(ty1, py1);
            float rbx = fminf(tx2, px2), rby = fminf(ty2, py2);
            float w_ = fmaxf(rbx - ltx, 0.0f), h_ = fmaxf(rby - lty, 0.0f);
            float inter = w_ * h_;
            float a1 = (tx2 - tx1) * (ty2 - ty1);
            float a2 = (px2 - px1) * (py2 - py1);
            iou[bx] = inter / (a1 + a2 - inter + 0.0001f);
        }
        const int best = (iou[1] > iou[0]) ? 1 : 0;   // argmax, ties -> 0
        const float pr = best ? p1 : p0;              // pred_resp already loaded
        const float dr = pr - iou[best];
        respAcc = dr * dr;
        #pragma unroll
        for (int k = 0; k < 4; ++k) {
            float d2 = p[best * 4 + k] - t[best * 4 + k];
            offAcc += d2 * d2;
        }
    }

    // ---- block reduction, one float4 store per block ----
    #pragma unroll
    for (int o = 32; o > 0; o >>= 1) {
        negAcc  += __shfl_down(negAcc,  o, 64);
        clsAcc  += __shfl_down(clsAcc,  o, 64);
        respAcc += __shfl_down(respAcc, o, 64);
        offAcc  += __shfl_down(offAcc,  o, 64);
    }
    __shared__ float4 s[NTHR / 64];
    if ((tid & 63) == 0) s[tid >> 6] = make_float4(negAcc, clsAcc, respAcc, offAcc);
    __syncthreads();
    if (tid == 0) {
        float4 tt = s[0];
        #pragma unroll
        for (int w = 1; w < NTHR / 64; ++w) {
            tt.x += s[w].x; tt.y += s[w].y; tt.z += s[w].z; tt.w += s[w].w;
        }
        partials[blockIdx.x] = tt;
        __threadfence();                              // release: partial visible
        unsigned old = atomicAdd(ticket, 1u);         // device-scope
        s_last = (old == NBLK - 1) ? 1 : 0;
    }
    __syncthreads();

    // ---- last-finishing block reduces all partials and writes out ----
    if (s_last) {
        __threadfence();                              // acquire: invalidate caches
        double neg = 0.0, cls = 0.0, resp = 0.0, offs = 0.0;
        for (int k = tid; k < NBLK; k += NTHR) {
            float4 v = partials[k];
            neg += (double)v.x; cls += (double)v.y;
            resp += (double)v.z; offs += (double)v.w;
        }
        #pragma unroll
        for (int o = 32; o > 0; o >>= 1) {
            neg  += __shfl_down(neg,  o, 64);
            cls  += __shfl_down(cls,  o, 64);
            resp += __shfl_down(resp, o, 64);
            offs += __shfl_down(offs, o, 64);
        }
        __shared__ double sd[4][NTHR / 64];
        const int w = tid >> 6;
        if ((tid & 63) == 0) { sd[0][w] = neg; sd[1][w] = cls; sd[2][w] = resp; sd[3][w] = offs; }
        __syncthreads();
        if (tid == 0) {
            double N = 0, C = 0, R = 0, O = 0;
            #pragma unroll
            for (int k = 0; k < NTHR / 64; ++k) {
                N += sd[0][k]; C += sd[1][k]; R += sd[2][k]; O += sd[3][k];
            }
            out[0] = (float)(R / (double)BATCH);        // pObj   (L_OBJ = 1)
            out[1] = (float)(N / (double)BATCH * 0.5);  // nObj   (L_NOOBJ)
            out[2] = (float)(C / (double)BATCH);        // cls
            out[3] = (float)(O / (double)BATCH * 5.0);  // off    (L_COORD)
        }
    }
}

extern "C" void kernel_launch(void* const* d_in, const int* in_sizes, int n_in,
                              void* d_out, int out_size, void* d_ws, size_t ws_size,
                              hipStream_t stream) {
    const float* pred_cls   = (const float*)d_in[0];
    const float* pred_resp  = (const float*)d_in[1];
    const float* pred_box   = (const float*)d_in[2];
    const float* label_cls  = (const float*)d_in[3];
    const float* label_resp = (const float*)d_in[4];
    const float* label_box  = (const float*)d_in[5];

    unsigned* ticket  = (unsigned*)d_ws;
    float4* partials  = (float4*)((char*)d_ws + 64);
    float* out = (float*)d_out;

    hipMemsetAsync(ticket, 0, sizeof(unsigned), stream);

    yolo_onepass_kernel<<<NBLK, NTHR, 0, stream>>>(
        pred_cls, pred_resp, pred_box, label_cls, label_resp, label_box,
        ticket, partials, out);
}

// Round 8
// 16.398 us; speedup vs baseline: 2.6776x; 2.6776x over previous
//
#include <hip/hip_runtime.h>

#define BATCH 64
#define CLSN 80
#define BBOXN 2
#define HWN (56 * 56)
#define NCELLS (BATCH * HWN)        // 200704
#define NTHR 256
#define HALF (NCELLS / 2)           // 100352
#define NBLK (HALF / NTHR)          // 392, exact

// ws layout: float4 partials[NBLK]  {neg, cls, resp, off}

__device__ __forceinline__ void boxLoss(const float* __restrict__ t,
                                        const float* __restrict__ p,
                                        float p0, float p1,
                                        float& respAcc, float& offAcc) {
    float iou[2];
    #pragma unroll
    for (int bx = 0; bx < 2; ++bx) {
        float tx1 = t[bx * 4 + 0] - t[bx * 4 + 2] * 0.5f;
        float ty1 = t[bx * 4 + 1] - t[bx * 4 + 3] * 0.5f;
        float tx2 = tx1 + t[bx * 4 + 2];
        float ty2 = ty1 + t[bx * 4 + 3];
        float px1 = p[bx * 4 + 0] - p[bx * 4 + 2] * 0.5f;
        float py1 = p[bx * 4 + 1] - p[bx * 4 + 3] * 0.5f;
        float px2 = px1 + p[bx * 4 + 2];
        float py2 = py1 + p[bx * 4 + 3];
        float ltx = fmaxf(tx1, px1), lty = fmaxf(ty1, py1);
        float rbx = fminf(tx2, px2), rby = fminf(ty2, py2);
        float w_ = fmaxf(rbx - ltx, 0.0f), h_ = fmaxf(rby - lty, 0.0f);
        float inter = w_ * h_;
        float a1 = (tx2 - tx1) * (ty2 - ty1);
        float a2 = (px2 - px1) * (py2 - py1);
        iou[bx] = inter / (a1 + a2 - inter + 0.0001f);
    }
    const int best = (iou[1] > iou[0]) ? 1 : 0;   // argmax, ties -> 0
    const float pr = best ? p1 : p0;
    const float dr = pr - iou[best];
    respAcc += dr * dr;
    #pragma unroll
    for (int k = 0; k < 4; ++k) {
        float d2 = p[best * 4 + k] - t[best * 4 + k];
        offAcc += d2 * d2;
    }
}

__global__ __launch_bounds__(NTHR)
void yolo_fused_kernel(const float* __restrict__ pred_cls,
                       const float* __restrict__ pred_resp,
                       const float* __restrict__ pred_box,
                       const float* __restrict__ label_cls,
                       const float* __restrict__ label_resp,
                       const float* __restrict__ label_box,
                       float4* __restrict__ partials) {
    __shared__ int s_cnt;
    __shared__ int s_list[128];      // cbase = b*CLSN*HWN + yx per selected cell

    const int tid = threadIdx.x;
    if (tid == 0) s_cnt = 0;

    // two cells per thread, one from each half of the flat index space;
    // both are coalesced across consecutive threads
    const int i0 = blockIdx.x * NTHR + tid;
    const int i1 = i0 + HALF;
    const int b0 = i0 / HWN, yx0 = i0 - b0 * HWN;
    const int b1 = i1 / HWN, yx1 = i1 - b1 * HWN;
    const int r0 = b0 * (BBOXN * HWN) + yx0;
    const int r1 = b1 * (BBOXN * HWN) + yx1;

    // 8 independent response loads in flight
    const float l0a = label_resp[r0], l1a = label_resp[r0 + HWN];
    const float p0a = pred_resp[r0],  p1a = pred_resp[r0 + HWN];
    const float l0b = label_resp[r1], l1b = label_resp[r1 + HWN];
    const float p0b = pred_resp[r1],  p1b = pred_resp[r1 + HWN];

    float negAcc = 0.0f, clsAcc = 0.0f, respAcc = 0.0f, offAcc = 0.0f;
    if (l0a < 1.0f) { float d = p0a - l0a; negAcc += d * d; }
    if (l1a < 1.0f) { float d = p1a - l1a; negAcc += d * d; }
    if (l0b < 1.0f) { float d = p0b - l0b; negAcc += d * d; }
    if (l1b < 1.0f) { float d = p1b - l1b; negAcc += d * d; }

    const bool selA = (l0a + l1a) >= 0.5f;
    const bool selB = (l0b + l1b) >= 0.5f;

    // ---- issue the scattered box loads EARLY; consume after the cls phase ----
    float tA[8], pA[8], tB[8], pB[8];
    if (selA) {
        const int bb = b0 * (BBOXN * 4) * HWN + yx0;
        #pragma unroll
        for (int k = 0; k < 8; ++k) {
            tA[k] = label_box[bb + k * HWN];
            pA[k] = pred_box[bb + k * HWN];
        }
    }
    if (selB) {
        const int bb = b1 * (BBOXN * 4) * HWN + yx1;
        #pragma unroll
        for (int k = 0; k < 8; ++k) {
            tB[k] = label_box[bb + k * HWN];
            pB[k] = pred_box[bb + k * HWN];
        }
    }

    __syncthreads();                 // s_cnt = 0 visible
    if (selA) {
        int slot = atomicAdd(&s_cnt, 1);
        s_list[slot] = b0 * (CLSN * HWN) + yx0;
    }
    if (selB) {
        int slot = atomicAdd(&s_cnt, 1);
        s_list[slot] = b1 * (CLSN * HWN) + yx1;
    }
    __syncthreads();
    const int nsel = s_cnt;          // block-uniform, avg ~5.2

    // ---- classification loss: block-cooperative, 3 cells x 80 classes/round,
    //      2 rounds unrolled so up to 4 independent loads are in flight ----
    const int cslot = tid / CLSN;    // 0..3 (3 full slots, tid<240)
    const int ccls  = tid - cslot * CLSN;
    const bool lane_ok = (tid < 3 * CLSN);
    for (int r = 0; r < nsel; r += 6) {
        const int sA = r + cslot;
        const int sB = r + cslot + 3;
        const bool aA = lane_ok && (sA < nsel);
        const bool aB = lane_ok && (sB < nsel);
        float qA = 0.0f, mA = 0.0f, qB = 0.0f, mB = 0.0f;
        if (aA) {
            const int ofs = s_list[sA] + ccls * HWN;
            qA = pred_cls[ofs]; mA = label_cls[ofs];
        }
        if (aB) {
            const int ofs = s_list[sB] + ccls * HWN;
            qB = pred_cls[ofs]; mB = label_cls[ofs];
        }
        if (aA) { float d = qA - mA; clsAcc += d * d; }
        if (aB) { float d = qB - mB; clsAcc += d * d; }
    }

    // ---- box / response loss: consume the early-issued loads ----
    if (selA) boxLoss(tA, pA, p0a, p1a, respAcc, offAcc);
    if (selB) boxLoss(tB, pB, p0b, p1b, respAcc, offAcc);

    // ---- block reduction, one float4 store per block ----
    #pragma unroll
    for (int o = 32; o > 0; o >>= 1) {
        negAcc  += __shfl_down(negAcc,  o, 64);
        clsAcc  += __shfl_down(clsAcc,  o, 64);
        respAcc += __shfl_down(respAcc, o, 64);
        offAcc  += __shfl_down(offAcc,  o, 64);
    }
    __shared__ float4 s[NTHR / 64];
    if ((tid & 63) == 0) s[tid >> 6] = make_float4(negAcc, clsAcc, respAcc, offAcc);
    __syncthreads();
    if (tid == 0) {
        float4 tt = s[0];
        #pragma unroll
        for (int w = 1; w < NTHR / 64; ++w) {
            tt.x += s[w].x; tt.y += s[w].y; tt.z += s[w].z; tt.w += s[w].w;
        }
        partials[blockIdx.x] = tt;
    }
}

__global__ void yolo_finalize_kernel(const float4* __restrict__ partials,
                                     float* __restrict__ out) {
    const int tid = threadIdx.x;
    double neg = 0.0, cls = 0.0, resp = 0.0, offs = 0.0;
    for (int k = tid; k < NBLK; k += NTHR) {
        float4 t = partials[k];
        neg += (double)t.x; cls += (double)t.y;
        resp += (double)t.z; offs += (double)t.w;
    }
    #pragma unroll
    for (int o = 32; o > 0; o >>= 1) {
        neg  += __shfl_down(neg,  o, 64);
        cls  += __shfl_down(cls,  o, 64);
        resp += __shfl_down(resp, o, 64);
        offs += __shfl_down(offs, o, 64);
    }
    __shared__ double s[4][NTHR / 64];
    const int w = tid >> 6;
    if ((tid & 63) == 0) { s[0][w] = neg; s[1][w] = cls; s[2][w] = resp; s[3][w] = offs; }
    __syncthreads();
    if (tid == 0) {
        double N = 0, C = 0, R = 0, O = 0;
        #pragma unroll
        for (int k = 0; k < NTHR / 64; ++k) {
            N += s[0][k]; C += s[1][k]; R += s[2][k]; O += s[3][k];
        }
        out[0] = (float)(R / (double)BATCH);        // pObj   (L_OBJ = 1)
        out[1] = (float)(N / (double)BATCH * 0.5);  // nObj   (L_NOOBJ)
        out[2] = (float)(C / (double)BATCH);        // cls
        out[3] = (float)(O / (double)BATCH * 5.0);  // off    (L_COORD)
    }
}

extern "C" void kernel_launch(void* const* d_in, const int* in_sizes, int n_in,
                              void* d_out, int out_size, void* d_ws, size_t ws_size,
                              hipStream_t stream) {
    const float* pred_cls   = (const float*)d_in[0];
    const float* pred_resp  = (const float*)d_in[1];
    const float* pred_box   = (const float*)d_in[2];
    const float* label_cls  = (const float*)d_in[3];
    const float* label_resp = (const float*)d_in[4];
    const float* label_box  = (const float*)d_in[5];

    float4* partials = (float4*)d_ws;
    float* out = (float*)d_out;

    yolo_fused_kernel<<<NBLK, NTHR, 0, stream>>>(
        pred_cls, pred_resp, pred_box, label_cls, label_resp, label_box, partials);

    yolo_finalize_kernel<<<1, NTHR, 0, stream>>>(partials, out);
}

// Round 9
// 15.468 us; speedup vs baseline: 2.8385x; 1.0601x over previous
//
#include <hip/hip_runtime.h>

#define BATCH 64
#define CLSN 80
#define BBOXN 2
#define HWN (56 * 56)
#define NCELLS (BATCH * HWN)   // 200704
#define NTHR 256
#define NBLK (NCELLS / NTHR)   // 784, exact

// ws layout: float4 partials[NBLK]  {neg, cls, resp, off}

__global__ void yolo_fused_kernel(const float* __restrict__ pred_cls,
                                  const float* __restrict__ pred_resp,
                                  const float* __restrict__ pred_box,
                                  const float* __restrict__ label_cls,
                                  const float* __restrict__ label_resp,
                                  const float* __restrict__ label_box,
                                  float4* __restrict__ partials) {
    __shared__ int s_cnt;
    __shared__ int s_list[128];          // cbase = b*CLSN*HWN + yx per selected cell

    const int tid = threadIdx.x;
    if (tid == 0) s_cnt = 0;

    const int i = blockIdx.x * NTHR + tid;          // grid covers NCELLS exactly
    const int b = i / HWN;
    const int yx = i - b * HWN;
    const int rbase = b * (BBOXN * HWN) + yx;

    // coalesced: consecutive threads -> consecutive yx
    const float l0 = label_resp[rbase];
    const float l1 = label_resp[rbase + HWN];
    const float p0 = pred_resp[rbase];
    const float p1 = pred_resp[rbase + HWN];

    float negAcc = 0.0f, clsAcc = 0.0f, respAcc = 0.0f, offAcc = 0.0f;
    if (l0 < 1.0f) { float d = p0 - l0; negAcc += d * d; }
    if (l1 < 1.0f) { float d = p1 - l1; negAcc += d * d; }

    const bool sel = (l0 + l1) >= 0.5f;

    // ---- issue the scattered box loads EARLY; consume after the cls phase ----
    float t[8], p[8];
    if (sel) {
        const int bbase = b * (BBOXN * 4) * HWN + yx;
        #pragma unroll
        for (int k = 0; k < 8; ++k) {
            t[k] = label_box[bbase + k * HWN];
            p[k] = pred_box[bbase + k * HWN];
        }
    }

    __syncthreads();                     // s_cnt = 0 visible to all
    if (sel) {
        int slot = atomicAdd(&s_cnt, 1); // LDS atomic, ~2.6 per block
        s_list[slot] = b * (CLSN * HWN) + yx;
    }
    __syncthreads();
    const int nsel = s_cnt;              // block-uniform

    // ---- classification loss: block-cooperative, 3 cells x 80 classes/round,
    //      2 rounds unrolled so up to 4 independent loads are in flight ----
    const int cslot = tid / CLSN;        // 0..3 (3 full slots, tid<240)
    const int ccls  = tid - cslot * CLSN;
    const bool lane_ok = (tid < 3 * CLSN);
    for (int r = 0; r < nsel; r += 6) {
        const int sA = r + cslot;
        const int sB = r + cslot + 3;
        const bool aA = lane_ok && (sA < nsel);
        const bool aB = lane_ok && (sB < nsel);
        float pA = 0.0f, lA = 0.0f, pB = 0.0f, lB = 0.0f;
        if (aA) {
            const int ofs = s_list[sA] + ccls * HWN;
            pA = pred_cls[ofs]; lA = label_cls[ofs];
        }
        if (aB) {
            const int ofs = s_list[sB] + ccls * HWN;
            pB = pred_cls[ofs]; lB = label_cls[ofs];
        }
        if (aA) { float d = pA - lA; clsAcc += d * d; }
        if (aB) { float d = pB - lB; clsAcc += d * d; }
    }

    // ---- box / response loss: consume the early-issued loads ----
    if (sel) {
        float iou[2];
        #pragma unroll
        for (int bx = 0; bx < 2; ++bx) {
            float tx1 = t[bx * 4 + 0] - t[bx * 4 + 2] * 0.5f;
            float ty1 = t[bx * 4 + 1] - t[bx * 4 + 3] * 0.5f;
            float tx2 = tx1 + t[bx * 4 + 2];
            float ty2 = ty1 + t[bx * 4 + 3];
            float px1 = p[bx * 4 + 0] - p[bx * 4 + 2] * 0.5f;
            float py1 = p[bx * 4 + 1] - p[bx * 4 + 3] * 0.5f;
            float px2 = px1 + p[bx * 4 + 2];
            float py2 = py1 + p[bx * 4 + 3];
            float ltx = fmaxf(tx1, px1), lty = fmaxf(ty1, py1);
            float rbx = fminf(tx2, px2), rby = fminf(ty2, py2);
            float w_ = fmaxf(rbx - ltx, 0.0f), h_ = fmaxf(rby - lty, 0.0f);
            float inter = w_ * h_;
            float a1 = (tx2 - tx1) * (ty2 - ty1);
            float a2 = (px2 - px1) * (py2 - py1);
            iou[bx] = inter / (a1 + a2 - inter + 0.0001f);
        }
        const int best = (iou[1] > iou[0]) ? 1 : 0;   // argmax, ties -> 0
        const float pr = best ? p1 : p0;              // pred_resp already loaded
        const float dr = pr - iou[best];
        respAcc = dr * dr;
        #pragma unroll
        for (int k = 0; k < 4; ++k) {
            float d2 = p[best * 4 + k] - t[best * 4 + k];
            offAcc += d2 * d2;
        }
    }

    // ---- block reduction, one float4 store per block ----
    #pragma unroll
    for (int o = 32; o > 0; o >>= 1) {
        negAcc  += __shfl_down(negAcc,  o, 64);
        clsAcc  += __shfl_down(clsAcc,  o, 64);
        respAcc += __shfl_down(respAcc, o, 64);
        offAcc  += __shfl_down(offAcc,  o, 64);
    }
    __shared__ float4 s[NTHR / 64];
    if ((tid & 63) == 0) s[tid >> 6] = make_float4(negAcc, clsAcc, respAcc, offAcc);
    __syncthreads();
    if (tid == 0) {
        float4 tt = s[0];
        #pragma unroll
        for (int w = 1; w < NTHR / 64; ++w) {
            tt.x += s[w].x; tt.y += s[w].y; tt.z += s[w].z; tt.w += s[w].w;
        }
        partials[blockIdx.x] = tt;
    }
}

__global__ void yolo_finalize_kernel(const float4* __restrict__ partials,
                                     float* __restrict__ out) {
    const int tid = threadIdx.x;
    double neg = 0.0, cls = 0.0, resp = 0.0, offs = 0.0;
    for (int k = tid; k < NBLK; k += NTHR) {
        float4 t = partials[k];
        neg += (double)t.x; cls += (double)t.y;
        resp += (double)t.z; offs += (double)t.w;
    }
    #pragma unroll
    for (int o = 32; o > 0; o >>= 1) {
        neg  += __shfl_down(neg,  o, 64);
        cls  += __shfl_down(cls,  o, 64);
        resp += __shfl_down(resp, o, 64);
        offs += __shfl_down(offs, o, 64);
    }
    __shared__ double s[4][NTHR / 64];
    const int w = tid >> 6;
    if ((tid & 63) == 0) { s[0][w] = neg; s[1][w] = cls; s[2][w] = resp; s[3][w] = offs; }
    __syncthreads();
    if (tid == 0) {
        double N = 0, C = 0, R = 0, O = 0;
        #pragma unroll
        for (int k = 0; k < NTHR / 64; ++k) {
            N += s[0][k]; C += s[1][k]; R += s[2][k]; O += s[3][k];
        }
        out[0] = (float)(R / (double)BATCH);        // pObj   (L_OBJ = 1)
        out[1] = (float)(N / (double)BATCH * 0.5);  // nObj   (L_NOOBJ)
        out[2] = (float)(C / (double)BATCH);        // cls
        out[3] = (float)(O / (double)BATCH * 5.0);  // off    (L_COORD)
    }
}

extern "C" void kernel_launch(void* const* d_in, const int* in_sizes, int n_in,
                              void* d_out, int out_size, void* d_ws, size_t ws_size,
                              hipStream_t stream) {
    const float* pred_cls   = (const float*)d_in[0];
    const float* pred_resp  = (const float*)d_in[1];
    const float* pred_box   = (const float*)d_in[2];
    const float* label_cls  = (const float*)d_in[3];
    const float* label_resp = (const float*)d_in[4];
    const float* label_box  = (const float*)d_in[5];

    float4* partials = (float4*)d_ws;
    float* out = (float*)d_out;

    yolo_fused_kernel<<<NBLK, NTHR, 0, stream>>>(
        pred_cls, pred_resp, pred_box, label_cls, label_resp, label_box, partials);

    yolo_finalize_kernel<<<1, NTHR, 0, stream>>>(partials, out);
}